// Round 7
// baseline (768.119 us; speedup 1.0000x reference)
//
#include <hip/hip_runtime.h>

#define NSRC 100000
#define NTGT 50000
#define NE   600000
#define CH   128
#define NREL 7
#define NTYP 4
#define NP   (NREL * NTGT)           // 350000 (rel,dst) pairs
#define NB   ((NP + 1023) / 1024)    // 342 scan blocks
#define NTILE ((NTGT + 63) / 64)     // 782 dst tiles

typedef __attribute__((ext_vector_type(4))) float f32x4;
typedef __attribute__((ext_vector_type(8))) short bf16x8;
typedef unsigned int uint;
typedef unsigned short ushort;

// ---- workspace layout ----
static constexpr size_t A256(size_t x) { return (x + 255) & ~(size_t)255; }
static constexpr size_t CNT_O   = 0;                                  // int[NP] (zeroed)
static constexpr size_t ZERO_END= A256(CNT_O + (size_t)NP * 4);
static constexpr size_t BSE_O   = ZERO_END;                           // int[NB]
static constexpr size_t BBE_O   = A256(BSE_O + (size_t)NB * 4);       // int[NB]
static constexpr size_t EOFF_O  = A256(BBE_O + (size_t)NB * 4);       // int[NP+1]
static constexpr size_t CUR_O   = A256(EOFF_O + (size_t)(NP + 64) * 4); // int[NP]
static constexpr size_t SEDGE_O = A256(CUR_O + (size_t)NP * 4);       // uint2[NE] 4.8MB
static constexpr size_t WB_O    = A256(SEDGE_O + (size_t)NE * 8);     // bf16[11*CH*CH]
static constexpr size_t XB_O    = A256(WB_O + (size_t)(NREL + NTYP) * CH * CH * 2);
static constexpr size_t XTB_O   = A256(XB_O + (size_t)NSRC * CH * 2);
static constexpr size_t MF_O    = A256(XTB_O + (size_t)NTGT * CH * 2); // fragged M: uint4[NTILE*4*28*64] ~90MB

__device__ __forceinline__ uint bfpack(float a, float b) {
  uint ua = __float_as_uint(a); ua = (ua + 0x7fff + ((ua >> 16) & 1)) >> 16;
  uint ub = __float_as_uint(b); ub = (ub + 0x7fff + ((ub >> 16) & 1)) >> 16;
  return ua | (ub << 16);
}
__device__ __forceinline__ ushort f2b(float x) {
  uint u = __float_as_uint(x);
  return (ushort)((u + 0x7fff + ((u >> 16) & 1)) >> 16);
}
__device__ __forceinline__ float bl(uint u) { return __uint_as_float(u << 16); }
__device__ __forceinline__ float bh(uint u) { return __uint_as_float(u & 0xffff0000u); }

__global__ void k_count(const int* __restrict__ edst, const int* __restrict__ etyp,
                        int* __restrict__ cnt) {
  int i = blockIdx.x * 256 + threadIdx.x;
  if (i < NE) atomicAdd(&cnt[etyp[i] * NTGT + edst[i]], 1);
}

// stage 1: per-1024-pair block sums of edge counts
__global__ __launch_bounds__(256) void k_s1(const int* __restrict__ cnt,
                                            int* __restrict__ bsE) {
  __shared__ int sE[256];
  int t = threadIdx.x, p0 = blockIdx.x * 1024 + t * 4;
  int e = 0;
#pragma unroll
  for (int j = 0; j < 4; ++j) {
    int p = p0 + j;
    if (p < NP) e += cnt[p];
  }
  sE[t] = e; __syncthreads();
  for (int s = 128; s > 0; s >>= 1) {
    if (t < s) sE[t] += sE[t + s];
    __syncthreads();
  }
  if (t == 0) bsE[blockIdx.x] = sE[0];
}

// stage 2: exclusive scan of block sums; seed eoff[NP]=NE
__global__ __launch_bounds__(512) void k_s2(const int* __restrict__ bsE,
                                            int* __restrict__ bbE, int* __restrict__ eoff) {
  __shared__ int sE[512];
  int t = threadIdx.x;
  int e = (t < NB) ? bsE[t] : 0;
  sE[t] = e; __syncthreads();
  for (int s = 1; s < 512; s <<= 1) {
    int ae = 0;
    if (t >= s) ae = sE[t - s];
    __syncthreads();
    sE[t] += ae;
    __syncthreads();
  }
  if (t < NB) bbE[t] = sE[t] - e;
  if (t == 0) eoff[NP] = NE;
}

// stage 3: per-pair edge offsets -> eoff (stable) + cur (bump pointers)
__global__ __launch_bounds__(256) void k_s3(const int* __restrict__ cnt,
    const int* __restrict__ bbE, int* __restrict__ eoff, int* __restrict__ cur) {
  __shared__ int sE[256];
  int t = threadIdx.x, p0 = blockIdx.x * 1024 + t * 4;
  int c[4]; int e = 0;
#pragma unroll
  for (int j = 0; j < 4; ++j) {
    int p = p0 + j;
    c[j] = (p < NP) ? cnt[p] : 0;
    e += c[j];
  }
  sE[t] = e; __syncthreads();
  for (int s = 1; s < 256; s <<= 1) {
    int ae = 0;
    if (t >= s) ae = sE[t - s];
    __syncthreads();
    sE[t] += ae;
    __syncthreads();
  }
  int baseE = bbE[blockIdx.x] + sE[t] - e;
#pragma unroll
  for (int j = 0; j < 4; ++j) {
    int p = p0 + j;
    if (p < NP) {
      eoff[p] = baseE; cur[p] = baseE;
      baseE += c[j];
    }
  }
}

// sort edges by (rel,dst); store (src, dst)
__global__ void k_esort(const int* __restrict__ esrc, const int* __restrict__ edst,
                        const int* __restrict__ etyp, int* __restrict__ cur,
                        uint2* __restrict__ sedge) {
  int i = blockIdx.x * 256 + threadIdx.x;
  if (i < NE) {
    int d = edst[i];
    int p = etyp[i] * NTGT + d;
    int pos = atomicAdd(&cur[p], 1);
    sedge[pos] = make_uint2((uint)esrc[i], (uint)d);
  }
}

// fp32 -> bf16 conversion (x_src, x_target, all weights)
__global__ void k_prep(const float* __restrict__ xsrc, const float* __restrict__ xt,
                       const float* __restrict__ relw, const float* __restrict__ rootw,
                       ushort* __restrict__ xb, ushort* __restrict__ xtb,
                       ushort* __restrict__ wb) {
  const long long NXB = (long long)NSRC * CH / 4;
  const long long NXT = (long long)NTGT * CH / 4;
  const long long NWR = (long long)NREL * CH * CH / 4;
  const long long NWT = (long long)NTYP * CH * CH / 4;
  long long i4 = (long long)blockIdx.x * 256 + threadIdx.x;
  const float* src; ushort* dst; long long off;
  if (i4 < NXB) { src = xsrc; dst = xb; off = i4; }
  else if (i4 < NXB + NXT) { src = xt; dst = xtb; off = i4 - NXB; }
  else if (i4 < NXB + NXT + NWR) { src = relw; dst = wb; off = i4 - NXB - NXT; }
  else if (i4 < NXB + NXT + NWR + NWT) {
    src = rootw; dst = wb + (size_t)NREL * CH * CH; off = i4 - NXB - NXT - NWR;
  } else return;
  float4 v = *(const float4*)(src + off * 4);
  uint lo = (uint)f2b(v.x) | ((uint)f2b(v.y) << 16);
  uint hi = (uint)f2b(v.z) | ((uint)f2b(v.w) << 16);
  *(uint2*)(dst + off * 4) = make_uint2(lo, hi);
}

// ---- k_agg: grid (NREL, NTILE). Edge-parallel LDS mean of 64 dsts for one rel,
// then pack MFMA A-frags and plain-store into fragged M (1KB/wave, coalesced).
// LDS layout: ch c of row -> row*128 + (c&1)*64 + (((c>>3) ^ (row&15))<<2) + ((c>>1)&3)
__global__ __launch_bounds__(256) void k_agg(const ushort* __restrict__ xb,
    const int* __restrict__ eoff, const uint2* __restrict__ sedge,
    uint4* __restrict__ mf) {
  __shared__ float agg[64 * CH];  // 32 KB
  int r = blockIdx.x, dt = blockIdx.y;
  int wv = threadIdx.x >> 6, ln = threadIdx.x & 63;
  int d0 = dt * 64;
  int dhi = (d0 + 64 < NTGT) ? d0 + 64 : NTGT;

#pragma unroll
  for (int i = 0; i < 8; ++i)
    ((f32x4*)agg)[i * 256 + threadIdx.x] = (f32x4){0.f, 0.f, 0.f, 0.f};
  __syncthreads();

  int elo = eoff[r * NTGT + d0];
  int ehi = eoff[r * NTGT + dhi];
  int cj = ln >> 2, wi = ln & 3;
  int i = elo + wv;
  for (; i + 12 < ehi; i += 16) {
    uint2 e0 = sedge[i], e1 = sedge[i + 4], e2 = sedge[i + 8], e3 = sedge[i + 12];
    uint x0 = *(const uint*)(xb + (size_t)e0.x * CH + (ln << 1));
    uint x1 = *(const uint*)(xb + (size_t)e1.x * CH + (ln << 1));
    uint x2 = *(const uint*)(xb + (size_t)e2.x * CH + (ln << 1));
    uint x3 = *(const uint*)(xb + (size_t)e3.x * CH + (ln << 1));
    int r0 = (int)e0.y - d0, r1 = (int)e1.y - d0;
    int r2 = (int)e2.y - d0, r3 = (int)e3.y - d0;
    int a0 = r0 * CH + ((cj ^ (r0 & 15)) << 2) + wi;
    int a1 = r1 * CH + ((cj ^ (r1 & 15)) << 2) + wi;
    int a2 = r2 * CH + ((cj ^ (r2 & 15)) << 2) + wi;
    int a3 = r3 * CH + ((cj ^ (r3 & 15)) << 2) + wi;
    atomicAdd(&agg[a0], bl(x0)); atomicAdd(&agg[a0 + 64], bh(x0));
    atomicAdd(&agg[a1], bl(x1)); atomicAdd(&agg[a1 + 64], bh(x1));
    atomicAdd(&agg[a2], bl(x2)); atomicAdd(&agg[a2 + 64], bh(x2));
    atomicAdd(&agg[a3], bl(x3)); atomicAdd(&agg[a3 + 64], bh(x3));
  }
  for (; i < ehi; i += 4) {
    uint2 e0 = sedge[i];
    uint x0 = *(const uint*)(xb + (size_t)e0.x * CH + (ln << 1));
    int r0 = (int)e0.y - d0;
    int a0 = r0 * CH + ((cj ^ (r0 & 15)) << 2) + wi;
    atomicAdd(&agg[a0], bl(x0)); atomicAdd(&agg[a0 + 64], bh(x0));
  }
  __syncthreads();

  // pack frags for rows wv*16+m, k-chunks kc*32+quad*8
  int m = ln & 15, quad = ln >> 4;
  int row = wv * 16 + m;
  int d = d0 + row;
  float inv = 0.f;
  if (d < dhi) {
    int p = r * NTGT + d;
    int c = eoff[p + 1] - eoff[p];
    inv = (c > 0) ? 1.0f / (float)c : 0.f;
  }
  size_t base = ((size_t)(dt * 4 + wv) * 28 + r * 4) * 64 + ln;
#pragma unroll
  for (int kc = 0; kc < 4; ++kc) {
    int t = kc * 4 + quad;
    f32x4 ev = *(const f32x4*)&agg[row * CH + ((t ^ m) << 2)];
    f32x4 od = *(const f32x4*)&agg[row * CH + 64 + ((t ^ m) << 2)];
    uint4 pk;
    pk.x = bfpack(ev.x * inv, od.x * inv);
    pk.y = bfpack(ev.y * inv, od.y * inv);
    pk.z = bfpack(ev.z * inv, od.z * inv);
    pk.w = bfpack(ev.w * inv, od.w * inv);
    mf[base + (size_t)kc * 64] = pk;
  }
}

// ---- k_gemm: grid (NTILE). out[64 x 128] = Mfrag(K=896) @ Wcat^T + root + bias.
__global__ __launch_bounds__(256) void k_gemm(const uint4* __restrict__ mf,
    const ushort* __restrict__ xtb, const ushort* __restrict__ wb,
    const int* __restrict__ ntyp, const float* __restrict__ rootb,
    float* __restrict__ out) {
  __shared__ float rb[NTYP * CH];  // 2 KB
  int dt = blockIdx.x;
  int wv = threadIdx.x >> 6, ln = threadIdx.x & 63;
  int m = ln & 15, quad = ln >> 4;
  int d0 = dt * 64;
  if (threadIdx.x < NTYP * CH / 4)
    ((f32x4*)rb)[threadIdx.x] = ((const f32x4*)rootb)[threadIdx.x];
  __syncthreads();

  f32x4 acc[8];
#pragma unroll
  for (int ct = 0; ct < 8; ++ct) acc[ct] = (f32x4){0.f, 0.f, 0.f, 0.f};

  // relation part: K = 7*128, A pre-fragged (coalesced 16B/lane)
  size_t abase = ((size_t)(dt * 4 + wv) * 28) * 64 + ln;
  for (int r = 0; r < NREL; ++r) {
    const ushort* W = wb + (size_t)r * CH * CH;
#pragma unroll
    for (int kc = 0; kc < 4; ++kc) {
      uint4 araw = mf[abase + (size_t)(r * 4 + kc) * 64];
      bf16x8 aF = *(bf16x8*)&araw;
#pragma unroll
      for (int ct = 0; ct < 8; ++ct) {
        bf16x8 bF = *(const bf16x8*)(W + (size_t)(ct * 16 + m) * CH + kc * 32 + quad * 8);
        acc[ct] = __builtin_amdgcn_mfma_f32_16x16x32_bf16(aF, bF, acc[ct], 0, 0, 0);
      }
    }
  }

  // root part: type-masked 4 passes
  int drow = d0 + wv * 16 + m;
  bool okr = drow < NTGT;
  int tmy = okr ? ntyp[drow] : -1;
  bf16x8 zf;
  *(uint4*)&zf = make_uint4(0, 0, 0, 0);
  bf16x8 aX[4];
#pragma unroll
  for (int ks = 0; ks < 4; ++ks)
    aX[ks] = okr ? *(const bf16x8*)(xtb + (size_t)drow * CH + ks * 32 + quad * 8) : zf;
#pragma unroll
  for (int t = 0; t < NTYP; ++t) {
    const ushort* W = wb + (size_t)(NREL + t) * CH * CH;
    bf16x8 aT[4];
#pragma unroll
    for (int ks = 0; ks < 4; ++ks) aT[ks] = (tmy == t) ? aX[ks] : zf;
#pragma unroll
    for (int ct = 0; ct < 8; ++ct) {
      int nn = ct * 16 + m;
#pragma unroll
      for (int ks = 0; ks < 4; ++ks) {
        bf16x8 bF = *(const bf16x8*)(W + (size_t)nn * CH + ks * 32 + quad * 8);
        acc[ct] = __builtin_amdgcn_mfma_f32_16x16x32_bf16(aT[ks], bF, acc[ct], 0, 0, 0);
      }
    }
  }

  // epilogue: bias + single plain store per element
#pragma unroll
  for (int reg = 0; reg < 4; ++reg) {
    int d = d0 + wv * 16 + quad * 4 + reg;
    if (d < NTGT) {
      int t = ntyp[d];
#pragma unroll
      for (int ct = 0; ct < 8; ++ct) {
        int col = ct * 16 + m;
        out[(size_t)d * CH + col] = acc[ct][reg] + rb[t * CH + col];
      }
    }
  }
}

extern "C" void kernel_launch(void* const* d_in, const int* in_sizes, int n_in,
                              void* d_out, int out_size, void* d_ws, size_t ws_size,
                              hipStream_t stream) {
  (void)in_sizes; (void)n_in; (void)out_size; (void)ws_size;
  const float* xsrc  = (const float*)d_in[0];
  const float* xt    = (const float*)d_in[1];
  const float* relw  = (const float*)d_in[2];
  const float* rootw = (const float*)d_in[3];
  const float* rootb = (const float*)d_in[4];
  const int* esrc = (const int*)d_in[5];
  const int* edst = (const int*)d_in[6];
  const int* etyp = (const int*)d_in[7];
  const int* ntyp = (const int*)d_in[8];
  float* out = (float*)d_out;

  char* ws = (char*)d_ws;
  int*   cnt   = (int*)(ws + CNT_O);
  int*   bsE   = (int*)(ws + BSE_O);
  int*   bbE   = (int*)(ws + BBE_O);
  int*   eoff  = (int*)(ws + EOFF_O);
  int*   cur   = (int*)(ws + CUR_O);
  uint2* sedge = (uint2*)(ws + SEDGE_O);
  ushort* wb   = (ushort*)(ws + WB_O);
  ushort* xb   = (ushort*)(ws + XB_O);
  ushort* xtb  = (ushort*)(ws + XTB_O);
  uint4* mf    = (uint4*)(ws + MF_O);

  hipMemsetAsync(ws, 0, ZERO_END, stream);
  k_count<<<dim3((NE + 255) / 256), dim3(256), 0, stream>>>(edst, etyp, cnt);
  k_s1<<<dim3(NB), dim3(256), 0, stream>>>(cnt, bsE);
  k_s2<<<dim3(1), dim3(512), 0, stream>>>(bsE, bbE, eoff);
  k_s3<<<dim3(NB), dim3(256), 0, stream>>>(cnt, bbE, eoff, cur);
  k_esort<<<dim3((NE + 255) / 256), dim3(256), 0, stream>>>(esrc, edst, etyp, cur, sedge);
  {
    long long tot4 = (long long)NSRC * CH / 4 + (long long)NTGT * CH / 4 +
                     (long long)(NREL + NTYP) * CH * CH / 4;
    k_prep<<<dim3((unsigned)((tot4 + 255) / 256)), dim3(256), 0, stream>>>(
        xsrc, xt, relw, rootw, xb, xtb, wb);
  }
  k_agg<<<dim3(NREL, NTILE), dim3(256), 0, stream>>>(xb, eoff, sedge, mf);
  k_gemm<<<dim3(NTILE), dim3(256), 0, stream>>>(mf, xtb, wb, ntyp, rootb, out);
}